// Round 16
// baseline (268.615 us; speedup 1.0000x reference)
//
#include <hip/hip_runtime.h>

constexpr int NB = 16;
constexpr int NCI = 64;
constexpr int NCO = 64;
constexpr int NH = 256;
constexpr int NW = 256;
constexpr int NM1 = 20;
constexpr int NM2 = 20;
constexpr int NMODES = 400;

// workspace layout (float offsets)
constexpr long OFF_TWS  = 0;                                  // fwd twiddle [256 w][48]
constexpr long OFF_TINV = 12288;                              // Tc[20][16][12] | Ts[20][16][12]
constexpr long OFF_XL   = OFF_TINV + 7680;                    // [2 half][NB*NCI][400][2]
constexpr long OFF_OL   = OFF_XL + 2L*NB*NCI*NMODES*2;        // [NB][NCO][400][2]

constexpr float TWO_PI = 6.28318530717958647692f;
constexpr float INV_N2 = 1.0f / 65536.0f;

// async global->LDS, 16 B per lane; LDS dest = wave-uniform base + lane*16
__device__ __forceinline__ void gload16(const float* g, float* l) {
    __builtin_amdgcn_global_load_lds(
        (const __attribute__((address_space(1))) unsigned int*)(g),
        (__attribute__((address_space(3))) unsigned int*)(l), 16, 0, 0);
}

// ---------------- table init ----------------------------------------------------
__global__ void init_tabs(float* __restrict__ ws) {
    int e = blockIdx.x * 256 + threadIdx.x;
    if (e < 12288) {
        int w = e / 48, s = e % 48;
        int cg = s / 12, q = s % 12;
        float v = 0.f;
        if (q < 10) {
            int n = 10 * cg + q, ky = n >> 1, p = n & 1;
            float ang = TWO_PI * (float)((ky * w) & 255) * (1.0f / 256.0f);
            float sn, cn; sincosf(ang, &sn, &cn);
            v = p ? -sn : cn;
        }
        ws[OFF_TWS + e] = v;
    } else if (e < 19968) {
        int f = e - 12288;
        int tb = f / 3840, rr = f % 3840;
        int ky = rr / 192, g = (rr % 192) / 12, q = rr % 12;
        float v = 0.f;
        if (q < 8) {
            int w = 8 * g + 1 + q;
            float ang = TWO_PI * (float)((ky * w) & 255) * (1.0f / 256.0f);
            float sn, cn; sincosf(ang, &sn, &cn);
            float cky = (ky == 0) ? 1.0f : 2.0f;
            v = (tb == 0 ? cn : sn) * cky * INV_N2;
        }
        ws[OFF_TINV + f] = v;
    }
}

// ---------------- forward: x -> X_low partials (radix-2 W-DFT then H-DFT) -------
// grid 2048: block = (plane r, half s); 128 h-rows per block; 256 threads.
// (256,2): no spill (bound=3 caps VGPR ~84 and spills — 4-for-4 empirical).
// 22.5 KB LDS + ~75 VGPR -> 4 blocks/CU (2x the TLP of the full-plane version,
// which profiled latency-bound at 21.5% occupancy / 36% VALUBusy).
// Wave owns an n-slice (wave-uniform twiddles via scalar path); lane owns 2 rows.
// Phase 2 emits the PARTIAL H-DFT over this block's 128 rows; mix sums halves.
__launch_bounds__(256, 2)
__global__ void fwd_kernel(const float* __restrict__ x, float* __restrict__ ws) {
    __shared__ float sm[5632];           // 22528 B
    float* sA = sm;                      // [128][40] phase 2 (aliases dbuf 0..4095)
    float2* csp = (float2*)(sm + 5120);  // [256] cos/sin (persistent, disjoint)
    const int t = threadIdx.x;
    const int bi = blockIdx.x;
    const int r = bi >> 1;                    // plane = b*64+i
    const int s = bi & 1;                     // h-half
    const float* xr = x + ((long)r << 16) + (s << 15);   // rows 128s..128s+127

    const int wid  = t >> 6;                  // n-slice: n = 10*wid + q
    const int lane = t & 63;                  // rows: lane + 64*rr, rr in {0,1}
    const int widu = __builtin_amdgcn_readfirstlane(wid);
    const float* twsu = ws + OFF_TWS + 12 * widu;
    const int keyr = (lane >> 1) & 3;         // read swizzle key (rr-invariant)
    const bool swapEO = (wid & 1);            // ky parity flips with wid (ky=5wid+d)

    // staging constants: inst ii covers rows 16ii..16ii+15, 4 phys slots each
    const int jsrc = (lane & 3) ^ ((lane >> 3) & 3);          // logical slot at my dest
    const int srcoff = ((jsrc >> 1) << 2) + ((jsrc & 1) << 7); // {0,4,128,132}
    const int srow = lane >> 2;

    float acc[2][10];
#pragma unroll
    for (int a0 = 0; a0 < 2; a0++)
#pragma unroll
        for (int a1 = 0; a1 < 10; a1++) acc[a0][a1] = 0.f;

#define STAGE(KC, BUF)                                                         \
    {                                                                          \
        const float* xs_ = xr + (KC) * 8 + srcoff;                             \
        _Pragma("unroll")                                                      \
        for (int ii = 0; ii < 8; ++ii)                                         \
            gload16(xs_ + (long)(ii * 16 + srow) * NW, (BUF) + ii * 256);      \
    }

    {
        float ang = TWO_PI * (float)t * (1.0f / 256.0f);
        float sn, cn; sincosf(ang, &sn, &cn);
        csp[t] = make_float2(cn, sn);
    }
    STAGE(0, sm);
    __syncthreads();   // chunk 0 staged & visible

    for (int kc = 0; kc < 16; ++kc) {
        float* buf = sm + (kc & 1) * 2048;
        if (kc < 15) STAGE(kc + 1, sm + ((kc + 1) & 1) * 2048);
#pragma unroll
        for (int g = 0; g < 2; ++g) {
            float4 f4[2], b4[2];
#pragma unroll
            for (int rr = 0; rr < 2; ++rr) {
                const float* rp = buf + (lane + 64 * rr) * 16;
                f4[rr] = *(const float4*)(rp + 4 * ((2 * g)     ^ keyr));
                b4[rr] = *(const float4*)(rp + 4 * ((2 * g + 1) ^ keyr));
            }
#pragma unroll
            for (int e = 0; e < 4; ++e) {
                const float* tp = twsu + (long)(kc * 8 + 4 * g + e) * 48;
                float4 t0 = *(const float4*)(tp);
                float4 t1 = *(const float4*)(tp + 4);
                float4 t2 = *(const float4*)(tp + 8);
                float tv[10] = {t0.x,t0.y,t0.z,t0.w, t1.x,t1.y,t1.z,t1.w, t2.x,t2.y};
#pragma unroll
                for (int rr = 0; rr < 2; ++rr) {
                    float fv = f4[rr][e], bv = b4[rr][e];
                    float mu = fv + bv, mv = fv - bv;
                    float mE = swapEO ? mv : mu;
                    float mO = swapEO ? mu : mv;
                    acc[rr][0] += mE * tv[0];  acc[rr][1] += mE * tv[1];
                    acc[rr][2] += mO * tv[2];  acc[rr][3] += mO * tv[3];
                    acc[rr][4] += mE * tv[4];  acc[rr][5] += mE * tv[5];
                    acc[rr][6] += mO * tv[6];  acc[rr][7] += mO * tv[7];
                    acc[rr][8] += mE * tv[8];  acc[rr][9] += mE * tv[9];
                }
            }
        }
        __syncthreads();   // prefetch done (vmcnt drain); all waves done with buf
    }
#undef STAGE

    // write A[hl][n] to LDS (csp persists)
#pragma unroll
    for (int rr = 0; rr < 2; ++rr)
#pragma unroll
        for (int q = 0; q < 10; ++q)
            sA[(lane + 64 * rr) * 40 + 10 * wid + q] = acc[rr][q];
    __syncthreads();

    // phase 2 (partial): XLp[s][kx,ky] = sum_{hl<128} A[hl][.] e^{-2pi i kx h/256},
    // h = 128*s + hl
    if (t < 200) {
        const int p  = t >> 1;         // 0..99
        const int sh = t & 1;          // 64-row sub-half; partner = adjacent lane
        const int kxg = p / 10, kyg = p % 10;
        const int kx0 = 2 * kxg;
        float a2[8];
#pragma unroll
        for (int q = 0; q < 8; q++) a2[q] = 0.f;
        for (int it = 0; it < 64; ++it) {
            int hl = 64 * sh + it;
            int hg = 128 * s + hl;
            float4 a = *(const float4*)(sA + hl * 40 + 4 * kyg); // re0,im0,re1,im1
            int i0 = (kx0 * hg) & 255;
            int i1 = (i0 + hg) & 255;
            float2 cs0 = csp[i0];
            float2 cs1 = csp[i1];
            a2[0] += a.x*cs0.x + a.y*cs0.y;  a2[1] += a.y*cs0.x - a.x*cs0.y;
            a2[2] += a.z*cs0.x + a.w*cs0.y;  a2[3] += a.w*cs0.x - a.z*cs0.y;
            a2[4] += a.x*cs1.x + a.y*cs1.y;  a2[5] += a.y*cs1.x - a.x*cs1.y;
            a2[6] += a.z*cs1.x + a.w*cs1.y;  a2[7] += a.w*cs1.x - a.z*cs1.y;
        }
#pragma unroll
        for (int q = 0; q < 8; q++) a2[q] += __shfl_xor(a2[q], 1);
        if (sh == 0) {
            float* xl = ws + OFF_XL + ((long)s * (NB * NCI) + r) * (NMODES * 2);
            *(float4*)(xl + 2*(kx0*20 + 2*kyg))       = make_float4(a2[0],a2[1],a2[2],a2[3]);
            *(float4*)(xl + 2*((kx0+1)*20 + 2*kyg))   = make_float4(a2[4],a2[5],a2[6],a2[7]);
        }
    }
}

// ---------------- channel mix: OL[b,o,m] = sum_i (XLp0+XLp1)[b,i,m]*W[i,o,m] ----
// grid 1024: bo = b*64+o; no LDS, no barriers; direct L2-resident reads.
// thread t<200 owns modes {2t, 2t+1}.
__launch_bounds__(256, 4)
__global__ void mix_kernel(const float* __restrict__ wre, const float* __restrict__ wim,
                           float* __restrict__ ws) {
    const int t = threadIdx.x;
    const int bo = blockIdx.x;
    const int b = bo >> 6, o = bo & 63;
    if (t >= 200) return;
    const float* XL0 = ws + OFF_XL + (long)(b * 64) * 800 + 4 * t;
    const float* XL1 = XL0 + (long)(NB * NCI) * 800;
    const float* wrp = wre + (long)o * NMODES + 2 * t;
    const float* wip = wim + (long)o * NMODES + 2 * t;
    float4 a = make_float4(0.f, 0.f, 0.f, 0.f);
#pragma unroll 4
    for (int i = 0; i < 64; ++i) {
        float4 x0 = *(const float4*)(XL0 + (long)i * 800);
        float4 x1 = *(const float4*)(XL1 + (long)i * 800);
        float2 wrv = *(const float2*)(wrp + (long)i * (NCO * NMODES));
        float2 wiv = *(const float2*)(wip + (long)i * (NCO * NMODES));
        float xr0 = x0.x + x1.x, xi0 = x0.y + x1.y;
        float xr1 = x0.z + x1.z, xi1 = x0.w + x1.w;
        a.x += xr0 * wrv.x - xi0 * wiv.x;
        a.y += xr0 * wiv.x + xi0 * wrv.x;
        a.z += xr1 * wrv.y - xi1 * wiv.y;
        a.w += xr1 * wiv.y + xi1 * wrv.y;
    }
    *(float4*)(ws + OFF_OL + (long)bo * 800 + 4 * t) = a;
}

// ---------------- inverse: OL -> out (fused H-iDFT then symmetric W-iDFT) -------
// grid 4096: (bo, hq); 256 threads; 3 blocks/CU
__launch_bounds__(256, 3)
__global__ void inv_kernel(const float* __restrict__ ws, float* __restrict__ out) {
    __shared__ float sm2[11712];
    float* sOL = sm2;            // 800
    float* cs  = sm2 + 800;      // 512
    float* sYr = sm2 + 1312;     // [20][68]
    float* sYi = sm2 + 2672;     // [20][68]
    float* sTc = sm2 + 4032;     // [20][16][12]
    float* sTs = sm2 + 7872;     // [20][16][12]
    const int t = threadIdx.x;
    const int blk = blockIdx.x;
    const int bo = blk >> 2;     // b*64+o
    const int hq = blk & 3;

    { float ang = TWO_PI * (float)t * (1.0f/256.0f); float s,c; sincosf(ang,&s,&c);
      cs[2*t] = c; cs[2*t+1] = s; }
    {
        const float* OL = ws + OFF_OL + (long)bo * (NMODES * 2);
#pragma unroll
        for (int j = 0; j < 4; ++j) {
            int u = t + 256 * j;
            if (u < 800) sOL[u] = OL[u];
        }
        const float* TI = ws + OFF_TINV;
#pragma unroll
        for (int j = 0; j < 8; ++j) {
            int u = t + 256 * j;
            if (u < 1920) *(float4*)(sTc + 4*u) = *(const float4*)(TI + 4*u);
        }
    }
    __syncthreads();

    // phase 1: Yc[ky][h] = sum_kx OL[kx][ky] e^{+2pi i kx h/256}
    {
        int hloc = t >> 2, kyq = t & 3;
        int h = hq * 64 + hloc;
        float a[5][2];
#pragma unroll
        for (int kk = 0; kk < 5; kk++) { a[kk][0] = 0.f; a[kk][1] = 0.f; }
        for (int kx = 0; kx < NM1; ++kx) {
            int idx = (kx * h) & 255;
            float c = cs[2*idx], s = cs[2*idx+1];
#pragma unroll
            for (int kk = 0; kk < 5; ++kk) {
                int ky = kyq * 5 + kk;
                float pr = sOL[2*(kx*NM2 + ky)], pi = sOL[2*(kx*NM2 + ky) + 1];
                a[kk][0] += pr * c - pi * s;
                a[kk][1] += pr * s + pi * c;
            }
        }
#pragma unroll
        for (int kk = 0; kk < 5; ++kk) {
            int ky = kyq * 5 + kk;
            sYr[ky*68 + hloc] = a[kk][0];
            sYi[ky*68 + hloc] = a[kk][1];
        }
    }
    __syncthreads();

    // phase 2: U = sum_ky Yr*Tc, V = sum_ky Yi*Ts; out[w]=U-V, out[256-w]=U+V
    {
        const int lg = t & 15;
        const int hg = t >> 4;
        float U[4][8], V[4][8];
#pragma unroll
        for (int rr = 0; rr < 4; rr++)
#pragma unroll
            for (int c = 0; c < 8; c++) { U[rr][c] = 0.f; V[rr][c] = 0.f; }
        for (int ky = 0; ky < 20; ++ky) {
            float4 yr = *(const float4*)(sYr + ky*68 + 4*hg);
            float4 yi = *(const float4*)(sYi + ky*68 + 4*hg);
            const float* tcp = sTc + ky*192 + lg*12;
            const float* tsp = sTs + ky*192 + lg*12;
            float4 c0 = *(const float4*)(tcp), c1 = *(const float4*)(tcp + 4);
            float4 s0 = *(const float4*)(tsp), s1 = *(const float4*)(tsp + 4);
            float ya[4] = {yr.x, yr.y, yr.z, yr.w};
            float yb[4] = {yi.x, yi.y, yi.z, yi.w};
            float tc[8] = {c0.x,c0.y,c0.z,c0.w, c1.x,c1.y,c1.z,c1.w};
            float ts[8] = {s0.x,s0.y,s0.z,s0.w, s1.x,s1.y,s1.z,s1.w};
#pragma unroll
            for (int rr = 0; rr < 4; ++rr)
#pragma unroll
                for (int c = 0; c < 8; ++c) {
                    U[rr][c] += ya[rr] * tc[c];
                    V[rr][c] += yb[rr] * ts[c];
                }
        }
        float* orow0 = out + (long)bo * (NH*NW) + (long)(hq*64 + 4*hg) * NW;
#pragma unroll
        for (int rr = 0; rr < 4; ++rr) {
            float* orow = orow0 + (long)rr * NW;
            float L[8], F[8];
#pragma unroll
            for (int c = 0; c < 8; ++c) { L[c] = U[rr][c] - V[rr][c]; F[c] = U[rr][c] + V[rr][c]; }
            int wl = 8*lg + 1;
            orow[wl] = L[0];
            *(float2*)(orow + wl + 1) = make_float2(L[1], L[2]);
            *(float4*)(orow + wl + 3) = make_float4(L[3], L[4], L[5], L[6]);
            orow[wl + 7] = L[7];
            *(float4*)(orow + 252 - 8*lg) = make_float4(F[3], F[2], F[1], F[0]);
            *(float4*)(orow + 248 - 8*lg) = make_float4(F[7], F[6], F[5], F[4]);
        }
    }
    if (t < 64) {
        float sum = 0.f;
        for (int ky = 0; ky < 20; ++ky)
            sum += sYr[ky*68 + t] * ((ky == 0) ? 1.0f : 2.0f);
        out[(long)bo * (NH*NW) + (long)(hq*64 + t) * NW] = sum * INV_N2;
    }
}

extern "C" void kernel_launch(void* const* d_in, const int* in_sizes, int n_in,
                              void* d_out, int out_size, void* d_ws, size_t ws_size,
                              hipStream_t stream) {
    const float* x   = (const float*)d_in[0];
    const float* wre = (const float*)d_in[1];
    const float* wim = (const float*)d_in[2];
    float* out = (float*)d_out;
    float* ws  = (float*)d_ws;

    init_tabs<<<dim3(78), dim3(256), 0, stream>>>(ws);
    fwd_kernel<<<dim3(2 * NB * NCI), dim3(256), 0, stream>>>(x, ws);
    mix_kernel<<<dim3(1024), dim3(256), 0, stream>>>(wre, wim, ws);
    inv_kernel<<<dim3(NB * NCO * 4), dim3(256), 0, stream>>>(ws, out);
}

// Round 17
// 266.870 us; speedup vs baseline: 1.0065x; 1.0065x over previous
//
#include <hip/hip_runtime.h>

constexpr int NB = 16;
constexpr int NCI = 64;
constexpr int NCO = 64;
constexpr int NH = 256;
constexpr int NW = 256;
constexpr int NM1 = 20;
constexpr int NM2 = 20;
constexpr int NMODES = 400;

// workspace layout (float offsets)
constexpr long OFF_TWS  = 0;                                  // fwd twiddle [256 w][48]
constexpr long OFF_TINV = 12288;                              // Tc[20][16][12] | Ts[20][16][12]
constexpr long OFF_XL   = OFF_TINV + 7680;                    // [2 half][NB*NCI][400][2]
constexpr long OFF_OL   = OFF_XL + 2L*NB*NCI*NMODES*2;        // [NB][NCO][400][2]

constexpr float TWO_PI = 6.28318530717958647692f;
constexpr float INV_N2 = 1.0f / 65536.0f;

// async global->LDS, 16 B per lane; LDS dest = wave-uniform base + lane*16
__device__ __forceinline__ void gload16(const float* g, float* l) {
    __builtin_amdgcn_global_load_lds(
        (const __attribute__((address_space(1))) unsigned int*)(g),
        (__attribute__((address_space(3))) unsigned int*)(l), 16, 0, 0);
}

// ---------------- table init ----------------------------------------------------
__global__ void init_tabs(float* __restrict__ ws) {
    int e = blockIdx.x * 256 + threadIdx.x;
    if (e < 12288) {
        int w = e / 48, s = e % 48;
        int cg = s / 12, q = s % 12;
        float v = 0.f;
        if (q < 10) {
            int n = 10 * cg + q, ky = n >> 1, p = n & 1;
            float ang = TWO_PI * (float)((ky * w) & 255) * (1.0f / 256.0f);
            float sn, cn; sincosf(ang, &sn, &cn);
            v = p ? -sn : cn;
        }
        ws[OFF_TWS + e] = v;
    } else if (e < 19968) {
        int f = e - 12288;
        int tb = f / 3840, rr = f % 3840;
        int ky = rr / 192, g = (rr % 192) / 12, q = rr % 12;
        float v = 0.f;
        if (q < 8) {
            int w = 8 * g + 1 + q;
            float ang = TWO_PI * (float)((ky * w) & 255) * (1.0f / 256.0f);
            float sn, cn; sincosf(ang, &sn, &cn);
            float cky = (ky == 0) ? 1.0f : 2.0f;
            v = (tb == 0 ? cn : sn) * cky * INV_N2;
        }
        ws[OFF_TINV + f] = v;
    }
}

// ---------------- forward: x -> X_low partials (radix-2 W-DFT then H-DFT) -------
// grid 2048: block = (plane r, half s); 128 h-rows per block; 256 threads.
// 3-deep chunk pipeline with COUNTED vmcnt (never drains to 0 in the loop):
// each wave DMAs its OWN full chunk copy (redundant staging), so chunk
// readiness is per-wave -> s_waitcnt vmcnt(16) leaves the 2 prefetched
// chunks (8 loads each) in flight across the raw s_barrier. Race audit:
// barrier at top of iter kc guarantees all waves done compute(kc-1)
// before anyone STAGEs chunk kc+2 into the same (mod 3) buffer; cross-wave
// late DMA writes are byte-identical (benign).
// (256,2): no spill (bound=3 caps VGPR ~84 and spills — 4-for-4 empirical).
__launch_bounds__(256, 2)
__global__ void fwd_kernel(const float* __restrict__ x, float* __restrict__ ws) {
    __shared__ float sm[6656];           // 26624 B: 3x2048 dbuf | sA alias | csp
    float* sA = sm;                      // [128][40] phase 2 (aliases buffers)
    float2* csp = (float2*)(sm + 6144);  // [256] cos/sin (persistent, disjoint)
    const int t = threadIdx.x;
    const int bi = blockIdx.x;
    const int r = bi >> 1;                    // plane = b*64+i
    const int s = bi & 1;                     // h-half
    const float* xr = x + ((long)r << 16) + (s << 15);   // rows 128s..128s+127

    const int wid  = t >> 6;                  // n-slice: n = 10*wid + q
    const int lane = t & 63;                  // rows: lane + 64*rr, rr in {0,1}
    const int widu = __builtin_amdgcn_readfirstlane(wid);
    const float* twsu = ws + OFF_TWS + 12 * widu;
    const int keyr = (lane >> 1) & 3;         // read swizzle key (rr-invariant)
    const bool swapEO = (wid & 1);            // ky parity flips with wid (ky=5wid+d)

    // staging constants: inst ii covers rows 16ii..16ii+15, 4 phys slots each
    const int jsrc = (lane & 3) ^ ((lane >> 3) & 3);          // logical slot at my dest
    const int srcoff = ((jsrc >> 1) << 2) + ((jsrc & 1) << 7); // {0,4,128,132}
    const int srow = lane >> 2;

    float acc[2][10];
#pragma unroll
    for (int a0 = 0; a0 < 2; a0++)
#pragma unroll
        for (int a1 = 0; a1 < 10; a1++) acc[a0][a1] = 0.f;

#define STAGE(KC, BUF)                                                         \
    {                                                                          \
        const float* xs_ = xr + (KC) * 8 + srcoff;                             \
        _Pragma("unroll")                                                      \
        for (int ii = 0; ii < 8; ++ii)                                         \
            gload16(xs_ + (long)(ii * 16 + srow) * NW, (BUF) + ii * 256);      \
    }

    {
        float ang = TWO_PI * (float)t * (1.0f / 256.0f);
        float sn, cn; sincosf(ang, &sn, &cn);
        csp[t] = make_float2(cn, sn);
    }
    STAGE(0, sm);
    STAGE(1, sm + 2048);

    for (int kc = 0; kc < 16; ++kc) {
        asm volatile("s_barrier" ::: "memory");      // raw: no vmcnt drain
        if (kc < 14) {
            float* nb = sm + ((kc + 2) % 3) * 2048;
            STAGE(kc + 2, nb);
        }
        // wait for THIS wave's chunk-kc copy; keep kc+1/kc+2 loads in flight
        if (kc < 14)      asm volatile("s_waitcnt vmcnt(16)" ::: "memory");
        else if (kc == 14) asm volatile("s_waitcnt vmcnt(8)" ::: "memory");
        else               asm volatile("s_waitcnt vmcnt(0)" ::: "memory");

        float* buf = sm + (kc % 3) * 2048;
#pragma unroll
        for (int g = 0; g < 2; ++g) {
            float4 f4[2], b4[2];
#pragma unroll
            for (int rr = 0; rr < 2; ++rr) {
                const float* rp = buf + (lane + 64 * rr) * 16;
                f4[rr] = *(const float4*)(rp + 4 * ((2 * g)     ^ keyr));
                b4[rr] = *(const float4*)(rp + 4 * ((2 * g + 1) ^ keyr));
            }
#pragma unroll
            for (int e = 0; e < 4; ++e) {
                const float* tp = twsu + (long)(kc * 8 + 4 * g + e) * 48;
                float4 t0 = *(const float4*)(tp);
                float4 t1 = *(const float4*)(tp + 4);
                float4 t2 = *(const float4*)(tp + 8);
                float tv[10] = {t0.x,t0.y,t0.z,t0.w, t1.x,t1.y,t1.z,t1.w, t2.x,t2.y};
#pragma unroll
                for (int rr = 0; rr < 2; ++rr) {
                    float fv = f4[rr][e], bv = b4[rr][e];
                    float mu = fv + bv, mv = fv - bv;
                    float mE = swapEO ? mv : mu;
                    float mO = swapEO ? mu : mv;
                    acc[rr][0] += mE * tv[0];  acc[rr][1] += mE * tv[1];
                    acc[rr][2] += mO * tv[2];  acc[rr][3] += mO * tv[3];
                    acc[rr][4] += mE * tv[4];  acc[rr][5] += mE * tv[5];
                    acc[rr][6] += mO * tv[6];  acc[rr][7] += mO * tv[7];
                    acc[rr][8] += mE * tv[8];  acc[rr][9] += mE * tv[9];
                }
            }
        }
    }
#undef STAGE

    __syncthreads();   // all compute done before sA overwrites the buffers

    // write A[hl][n] to LDS (csp persists)
#pragma unroll
    for (int rr = 0; rr < 2; ++rr)
#pragma unroll
        for (int q = 0; q < 10; ++q)
            sA[(lane + 64 * rr) * 40 + 10 * wid + q] = acc[rr][q];
    __syncthreads();

    // phase 2 (partial): XLp[s][kx,ky] = sum_{hl<128} A[hl][.] e^{-2pi i kx h/256},
    // h = 128*s + hl
    if (t < 200) {
        const int p  = t >> 1;         // 0..99
        const int sh = t & 1;          // 64-row sub-half; partner = adjacent lane
        const int kxg = p / 10, kyg = p % 10;
        const int kx0 = 2 * kxg;
        float a2[8];
#pragma unroll
        for (int q = 0; q < 8; q++) a2[q] = 0.f;
        for (int it = 0; it < 64; ++it) {
            int hl = 64 * sh + it;
            int hg = 128 * s + hl;
            float4 a = *(const float4*)(sA + hl * 40 + 4 * kyg); // re0,im0,re1,im1
            int i0 = (kx0 * hg) & 255;
            int i1 = (i0 + hg) & 255;
            float2 cs0 = csp[i0];
            float2 cs1 = csp[i1];
            a2[0] += a.x*cs0.x + a.y*cs0.y;  a2[1] += a.y*cs0.x - a.x*cs0.y;
            a2[2] += a.z*cs0.x + a.w*cs0.y;  a2[3] += a.w*cs0.x - a.z*cs0.y;
            a2[4] += a.x*cs1.x + a.y*cs1.y;  a2[5] += a.y*cs1.x - a.x*cs1.y;
            a2[6] += a.z*cs1.x + a.w*cs1.y;  a2[7] += a.w*cs1.x - a.z*cs1.y;
        }
#pragma unroll
        for (int q = 0; q < 8; q++) a2[q] += __shfl_xor(a2[q], 1);
        if (sh == 0) {
            float* xl = ws + OFF_XL + ((long)s * (NB * NCI) + r) * (NMODES * 2);
            *(float4*)(xl + 2*(kx0*20 + 2*kyg))       = make_float4(a2[0],a2[1],a2[2],a2[3]);
            *(float4*)(xl + 2*((kx0+1)*20 + 2*kyg))   = make_float4(a2[4],a2[5],a2[6],a2[7]);
        }
    }
}

// ---------------- channel mix: OL[b,o,m] = sum_i (XLp0+XLp1)[b,i,m]*W[i,o,m] ----
// grid 1024: bo = b*64+o; no LDS, no barriers; direct L2-resident reads.
// thread t<200 owns modes {2t, 2t+1}.
__launch_bounds__(256, 4)
__global__ void mix_kernel(const float* __restrict__ wre, const float* __restrict__ wim,
                           float* __restrict__ ws) {
    const int t = threadIdx.x;
    const int bo = blockIdx.x;
    const int b = bo >> 6, o = bo & 63;
    if (t >= 200) return;
    const float* XL0 = ws + OFF_XL + (long)(b * 64) * 800 + 4 * t;
    const float* XL1 = XL0 + (long)(NB * NCI) * 800;
    const float* wrp = wre + (long)o * NMODES + 2 * t;
    const float* wip = wim + (long)o * NMODES + 2 * t;
    float4 a = make_float4(0.f, 0.f, 0.f, 0.f);
#pragma unroll 4
    for (int i = 0; i < 64; ++i) {
        float4 x0 = *(const float4*)(XL0 + (long)i * 800);
        float4 x1 = *(const float4*)(XL1 + (long)i * 800);
        float2 wrv = *(const float2*)(wrp + (long)i * (NCO * NMODES));
        float2 wiv = *(const float2*)(wip + (long)i * (NCO * NMODES));
        float xr0 = x0.x + x1.x, xi0 = x0.y + x1.y;
        float xr1 = x0.z + x1.z, xi1 = x0.w + x1.w;
        a.x += xr0 * wrv.x - xi0 * wiv.x;
        a.y += xr0 * wiv.x + xi0 * wrv.x;
        a.z += xr1 * wrv.y - xi1 * wiv.y;
        a.w += xr1 * wiv.y + xi1 * wrv.y;
    }
    *(float4*)(ws + OFF_OL + (long)bo * 800 + 4 * t) = a;
}

// ---------------- inverse: OL -> out (fused H-iDFT then symmetric W-iDFT) -------
// grid 4096: (bo, hq); 256 threads; 3 blocks/CU
__launch_bounds__(256, 3)
__global__ void inv_kernel(const float* __restrict__ ws, float* __restrict__ out) {
    __shared__ float sm2[11712];
    float* sOL = sm2;            // 800
    float* cs  = sm2 + 800;      // 512
    float* sYr = sm2 + 1312;     // [20][68]
    float* sYi = sm2 + 2672;     // [20][68]
    float* sTc = sm2 + 4032;     // [20][16][12]
    float* sTs = sm2 + 7872;     // [20][16][12]
    const int t = threadIdx.x;
    const int blk = blockIdx.x;
    const int bo = blk >> 2;     // b*64+o
    const int hq = blk & 3;

    { float ang = TWO_PI * (float)t * (1.0f/256.0f); float s,c; sincosf(ang,&s,&c);
      cs[2*t] = c; cs[2*t+1] = s; }
    {
        const float* OL = ws + OFF_OL + (long)bo * (NMODES * 2);
#pragma unroll
        for (int j = 0; j < 4; ++j) {
            int u = t + 256 * j;
            if (u < 800) sOL[u] = OL[u];
        }
        const float* TI = ws + OFF_TINV;
#pragma unroll
        for (int j = 0; j < 8; ++j) {
            int u = t + 256 * j;
            if (u < 1920) *(float4*)(sTc + 4*u) = *(const float4*)(TI + 4*u);
        }
    }
    __syncthreads();

    // phase 1: Yc[ky][h] = sum_kx OL[kx][ky] e^{+2pi i kx h/256}
    {
        int hloc = t >> 2, kyq = t & 3;
        int h = hq * 64 + hloc;
        float a[5][2];
#pragma unroll
        for (int kk = 0; kk < 5; kk++) { a[kk][0] = 0.f; a[kk][1] = 0.f; }
        for (int kx = 0; kx < NM1; ++kx) {
            int idx = (kx * h) & 255;
            float c = cs[2*idx], s = cs[2*idx+1];
#pragma unroll
            for (int kk = 0; kk < 5; ++kk) {
                int ky = kyq * 5 + kk;
                float pr = sOL[2*(kx*NM2 + ky)], pi = sOL[2*(kx*NM2 + ky) + 1];
                a[kk][0] += pr * c - pi * s;
                a[kk][1] += pr * s + pi * c;
            }
        }
#pragma unroll
        for (int kk = 0; kk < 5; ++kk) {
            int ky = kyq * 5 + kk;
            sYr[ky*68 + hloc] = a[kk][0];
            sYi[ky*68 + hloc] = a[kk][1];
        }
    }
    __syncthreads();

    // phase 2: U = sum_ky Yr*Tc, V = sum_ky Yi*Ts; out[w]=U-V, out[256-w]=U+V
    {
        const int lg = t & 15;
        const int hg = t >> 4;
        float U[4][8], V[4][8];
#pragma unroll
        for (int rr = 0; rr < 4; rr++)
#pragma unroll
            for (int c = 0; c < 8; c++) { U[rr][c] = 0.f; V[rr][c] = 0.f; }
        for (int ky = 0; ky < 20; ++ky) {
            float4 yr = *(const float4*)(sYr + ky*68 + 4*hg);
            float4 yi = *(const float4*)(sYi + ky*68 + 4*hg);
            const float* tcp = sTc + ky*192 + lg*12;
            const float* tsp = sTs + ky*192 + lg*12;
            float4 c0 = *(const float4*)(tcp), c1 = *(const float4*)(tcp + 4);
            float4 s0 = *(const float4*)(tsp), s1 = *(const float4*)(tsp + 4);
            float ya[4] = {yr.x, yr.y, yr.z, yr.w};
            float yb[4] = {yi.x, yi.y, yi.z, yi.w};
            float tc[8] = {c0.x,c0.y,c0.z,c0.w, c1.x,c1.y,c1.z,c1.w};
            float ts[8] = {s0.x,s0.y,s0.z,s0.w, s1.x,s1.y,s1.z,s1.w};
#pragma unroll
            for (int rr = 0; rr < 4; ++rr)
#pragma unroll
                for (int c = 0; c < 8; ++c) {
                    U[rr][c] += ya[rr] * tc[c];
                    V[rr][c] += yb[rr] * ts[c];
                }
        }
        float* orow0 = out + (long)bo * (NH*NW) + (long)(hq*64 + 4*hg) * NW;
#pragma unroll
        for (int rr = 0; rr < 4; ++rr) {
            float* orow = orow0 + (long)rr * NW;
            float L[8], F[8];
#pragma unroll
            for (int c = 0; c < 8; ++c) { L[c] = U[rr][c] - V[rr][c]; F[c] = U[rr][c] + V[rr][c]; }
            int wl = 8*lg + 1;
            orow[wl] = L[0];
            *(float2*)(orow + wl + 1) = make_float2(L[1], L[2]);
            *(float4*)(orow + wl + 3) = make_float4(L[3], L[4], L[5], L[6]);
            orow[wl + 7] = L[7];
            *(float4*)(orow + 252 - 8*lg) = make_float4(F[3], F[2], F[1], F[0]);
            *(float4*)(orow + 248 - 8*lg) = make_float4(F[7], F[6], F[5], F[4]);
        }
    }
    if (t < 64) {
        float sum = 0.f;
        for (int ky = 0; ky < 20; ++ky)
            sum += sYr[ky*68 + t] * ((ky == 0) ? 1.0f : 2.0f);
        out[(long)bo * (NH*NW) + (long)(hq*64 + t) * NW] = sum * INV_N2;
    }
}

extern "C" void kernel_launch(void* const* d_in, const int* in_sizes, int n_in,
                              void* d_out, int out_size, void* d_ws, size_t ws_size,
                              hipStream_t stream) {
    const float* x   = (const float*)d_in[0];
    const float* wre = (const float*)d_in[1];
    const float* wim = (const float*)d_in[2];
    float* out = (float*)d_out;
    float* ws  = (float*)d_ws;

    init_tabs<<<dim3(78), dim3(256), 0, stream>>>(ws);
    fwd_kernel<<<dim3(2 * NB * NCI), dim3(256), 0, stream>>>(x, ws);
    mix_kernel<<<dim3(1024), dim3(256), 0, stream>>>(wre, wim, ws);
    inv_kernel<<<dim3(NB * NCO * 4), dim3(256), 0, stream>>>(ws, out);
}

// Round 18
// 265.457 us; speedup vs baseline: 1.0119x; 1.0053x over previous
//
#include <hip/hip_runtime.h>

constexpr int NB = 16;
constexpr int NCI = 64;
constexpr int NCO = 64;
constexpr int NH = 256;
constexpr int NW = 256;
constexpr int NM1 = 20;
constexpr int NM2 = 20;
constexpr int NMODES = 400;

// workspace layout (float offsets)
constexpr long OFF_TWS  = 0;                                  // fwd twiddle [256 w][48]
constexpr long OFF_TINV = 12288;                              // Tc[20][16][12] | Ts[20][16][12]
constexpr long OFF_XL   = OFF_TINV + 7680;                    // [2 half][NB*NCI][400][2]
constexpr long OFF_OL   = OFF_XL + 2L*NB*NCI*NMODES*2;        // [NB][NCO][400][2]

constexpr float TWO_PI = 6.28318530717958647692f;
constexpr float INV_N2 = 1.0f / 65536.0f;

// async global->LDS, 16 B per lane; LDS dest = wave-uniform base + lane*16
__device__ __forceinline__ void gload16(const float* g, float* l) {
    __builtin_amdgcn_global_load_lds(
        (const __attribute__((address_space(1))) unsigned int*)(g),
        (__attribute__((address_space(3))) unsigned int*)(l), 16, 0, 0);
}

// ---------------- table init ----------------------------------------------------
__global__ void init_tabs(float* __restrict__ ws) {
    int e = blockIdx.x * 256 + threadIdx.x;
    if (e < 12288) {
        int w = e / 48, s = e % 48;
        int cg = s / 12, q = s % 12;
        float v = 0.f;
        if (q < 10) {
            int n = 10 * cg + q, ky = n >> 1, p = n & 1;
            float ang = TWO_PI * (float)((ky * w) & 255) * (1.0f / 256.0f);
            float sn, cn; sincosf(ang, &sn, &cn);
            v = p ? -sn : cn;
        }
        ws[OFF_TWS + e] = v;
    } else if (e < 19968) {
        int f = e - 12288;
        int tb = f / 3840, rr = f % 3840;
        int ky = rr / 192, g = (rr % 192) / 12, q = rr % 12;
        float v = 0.f;
        if (q < 8) {
            int w = 8 * g + 1 + q;
            float ang = TWO_PI * (float)((ky * w) & 255) * (1.0f / 256.0f);
            float sn, cn; sincosf(ang, &sn, &cn);
            float cky = (ky == 0) ? 1.0f : 2.0f;
            v = (tb == 0 ? cn : sn) * cky * INV_N2;
        }
        ws[OFF_TINV + f] = v;
    }
}

// ---------------- forward: x -> X_low partials (radix-2 W-DFT then H-DFT) -------
// grid 2048: block = (plane r, half s); 128 h-rows per block; 256 threads.
// 3-deep chunk pipeline with COUNTED vmcnt (never drains to 0 in the loop):
// each wave DMAs its OWN full chunk copy (redundant staging), so chunk
// readiness is per-wave -> s_waitcnt vmcnt(16) leaves the 2 prefetched
// chunks (8 loads each) in flight across the raw s_barrier. Race audit:
// barrier at top of iter kc guarantees all waves done compute(kc-1)
// before anyone STAGEs chunk kc+2 into the same (mod 3) buffer; cross-wave
// late DMA writes are byte-identical (benign).
// (256,2): no spill (bound=3 caps VGPR ~84 and spills — 4-for-4 empirical).
__launch_bounds__(256, 2)
__global__ void fwd_kernel(const float* __restrict__ x, float* __restrict__ ws) {
    __shared__ float sm[6656];           // 26624 B: 3x2048 dbuf | sA alias | csp
    float* sA = sm;                      // [128][40] phase 2 (aliases buffers)
    float2* csp = (float2*)(sm + 6144);  // [256] cos/sin (persistent, disjoint)
    const int t = threadIdx.x;
    const int bi = blockIdx.x;
    const int r = bi >> 1;                    // plane = b*64+i
    const int s = bi & 1;                     // h-half
    const float* xr = x + ((long)r << 16) + (s << 15);   // rows 128s..128s+127

    const int wid  = t >> 6;                  // n-slice: n = 10*wid + q
    const int lane = t & 63;                  // rows: lane + 64*rr, rr in {0,1}
    const int widu = __builtin_amdgcn_readfirstlane(wid);
    const float* twsu = ws + OFF_TWS + 12 * widu;
    const int keyr = (lane >> 1) & 3;         // read swizzle key (rr-invariant)
    const bool swapEO = (wid & 1);            // ky parity flips with wid (ky=5wid+d)

    // staging constants: inst ii covers rows 16ii..16ii+15, 4 phys slots each
    const int jsrc = (lane & 3) ^ ((lane >> 3) & 3);          // logical slot at my dest
    const int srcoff = ((jsrc >> 1) << 2) + ((jsrc & 1) << 7); // {0,4,128,132}
    const int srow = lane >> 2;

    float acc[2][10];
#pragma unroll
    for (int a0 = 0; a0 < 2; a0++)
#pragma unroll
        for (int a1 = 0; a1 < 10; a1++) acc[a0][a1] = 0.f;

#define STAGE(KC, BUF)                                                         \
    {                                                                          \
        const float* xs_ = xr + (KC) * 8 + srcoff;                             \
        _Pragma("unroll")                                                      \
        for (int ii = 0; ii < 8; ++ii)                                         \
            gload16(xs_ + (long)(ii * 16 + srow) * NW, (BUF) + ii * 256);      \
    }

    {
        float ang = TWO_PI * (float)t * (1.0f / 256.0f);
        float sn, cn; sincosf(ang, &sn, &cn);
        csp[t] = make_float2(cn, sn);
    }
    STAGE(0, sm);
    STAGE(1, sm + 2048);

    for (int kc = 0; kc < 16; ++kc) {
        asm volatile("s_barrier" ::: "memory");      // raw: no vmcnt drain
        if (kc < 14) {
            float* nb = sm + ((kc + 2) % 3) * 2048;
            STAGE(kc + 2, nb);
        }
        // wait for THIS wave's chunk-kc copy; keep kc+1/kc+2 loads in flight
        if (kc < 14)      asm volatile("s_waitcnt vmcnt(16)" ::: "memory");
        else if (kc == 14) asm volatile("s_waitcnt vmcnt(8)" ::: "memory");
        else               asm volatile("s_waitcnt vmcnt(0)" ::: "memory");

        float* buf = sm + (kc % 3) * 2048;
#pragma unroll
        for (int g = 0; g < 2; ++g) {
            float4 f4[2], b4[2];
#pragma unroll
            for (int rr = 0; rr < 2; ++rr) {
                const float* rp = buf + (lane + 64 * rr) * 16;
                f4[rr] = *(const float4*)(rp + 4 * ((2 * g)     ^ keyr));
                b4[rr] = *(const float4*)(rp + 4 * ((2 * g + 1) ^ keyr));
            }
#pragma unroll
            for (int e = 0; e < 4; ++e) {
                const float* tp = twsu + (long)(kc * 8 + 4 * g + e) * 48;
                float4 t0 = *(const float4*)(tp);
                float4 t1 = *(const float4*)(tp + 4);
                float4 t2 = *(const float4*)(tp + 8);
                float tv[10] = {t0.x,t0.y,t0.z,t0.w, t1.x,t1.y,t1.z,t1.w, t2.x,t2.y};
#pragma unroll
                for (int rr = 0; rr < 2; ++rr) {
                    float fv = f4[rr][e], bv = b4[rr][e];
                    float mu = fv + bv, mv = fv - bv;
                    float mE = swapEO ? mv : mu;
                    float mO = swapEO ? mu : mv;
                    acc[rr][0] += mE * tv[0];  acc[rr][1] += mE * tv[1];
                    acc[rr][2] += mO * tv[2];  acc[rr][3] += mO * tv[3];
                    acc[rr][4] += mE * tv[4];  acc[rr][5] += mE * tv[5];
                    acc[rr][6] += mO * tv[6];  acc[rr][7] += mO * tv[7];
                    acc[rr][8] += mE * tv[8];  acc[rr][9] += mE * tv[9];
                }
            }
        }
    }
#undef STAGE

    __syncthreads();   // all compute done before sA overwrites the buffers

    // write A[hl][n] to LDS (csp persists)
#pragma unroll
    for (int rr = 0; rr < 2; ++rr)
#pragma unroll
        for (int q = 0; q < 10; ++q)
            sA[(lane + 64 * rr) * 40 + 10 * wid + q] = acc[rr][q];
    __syncthreads();

    // phase 2 (partial): XLp[s][kx,ky] = sum_{hl<128} A[hl][.] e^{-2pi i kx h/256},
    // h = 128*s + hl
    if (t < 200) {
        const int p  = t >> 1;         // 0..99
        const int sh = t & 1;          // 64-row sub-half; partner = adjacent lane
        const int kxg = p / 10, kyg = p % 10;
        const int kx0 = 2 * kxg;
        float a2[8];
#pragma unroll
        for (int q = 0; q < 8; q++) a2[q] = 0.f;
        for (int it = 0; it < 64; ++it) {
            int hl = 64 * sh + it;
            int hg = 128 * s + hl;
            float4 a = *(const float4*)(sA + hl * 40 + 4 * kyg); // re0,im0,re1,im1
            int i0 = (kx0 * hg) & 255;
            int i1 = (i0 + hg) & 255;
            float2 cs0 = csp[i0];
            float2 cs1 = csp[i1];
            a2[0] += a.x*cs0.x + a.y*cs0.y;  a2[1] += a.y*cs0.x - a.x*cs0.y;
            a2[2] += a.z*cs0.x + a.w*cs0.y;  a2[3] += a.w*cs0.x - a.z*cs0.y;
            a2[4] += a.x*cs1.x + a.y*cs1.y;  a2[5] += a.y*cs1.x - a.x*cs1.y;
            a2[6] += a.z*cs1.x + a.w*cs1.y;  a2[7] += a.w*cs1.x - a.z*cs1.y;
        }
#pragma unroll
        for (int q = 0; q < 8; q++) a2[q] += __shfl_xor(a2[q], 1);
        if (sh == 0) {
            float* xl = ws + OFF_XL + ((long)s * (NB * NCI) + r) * (NMODES * 2);
            *(float4*)(xl + 2*(kx0*20 + 2*kyg))       = make_float4(a2[0],a2[1],a2[2],a2[3]);
            *(float4*)(xl + 2*((kx0+1)*20 + 2*kyg))   = make_float4(a2[4],a2[5],a2[6],a2[7]);
        }
    }
}

// ---------------- channel mix: OL[b,o,m] = sum_i (XLp0+XLp1)[b,i,m]*W[i,o,m] ----
// grid 1024: bo = b*64+o; no LDS, no barriers; direct L2-resident reads.
// thread t<200 owns modes {2t, 2t+1}.
__launch_bounds__(256, 4)
__global__ void mix_kernel(const float* __restrict__ wre, const float* __restrict__ wim,
                           float* __restrict__ ws) {
    const int t = threadIdx.x;
    const int bo = blockIdx.x;
    const int b = bo >> 6, o = bo & 63;
    if (t >= 200) return;
    const float* XL0 = ws + OFF_XL + (long)(b * 64) * 800 + 4 * t;
    const float* XL1 = XL0 + (long)(NB * NCI) * 800;
    const float* wrp = wre + (long)o * NMODES + 2 * t;
    const float* wip = wim + (long)o * NMODES + 2 * t;
    float4 a = make_float4(0.f, 0.f, 0.f, 0.f);
#pragma unroll 4
    for (int i = 0; i < 64; ++i) {
        float4 x0 = *(const float4*)(XL0 + (long)i * 800);
        float4 x1 = *(const float4*)(XL1 + (long)i * 800);
        float2 wrv = *(const float2*)(wrp + (long)i * (NCO * NMODES));
        float2 wiv = *(const float2*)(wip + (long)i * (NCO * NMODES));
        float xr0 = x0.x + x1.x, xi0 = x0.y + x1.y;
        float xr1 = x0.z + x1.z, xi1 = x0.w + x1.w;
        a.x += xr0 * wrv.x - xi0 * wiv.x;
        a.y += xr0 * wiv.x + xi0 * wrv.x;
        a.z += xr1 * wrv.y - xi1 * wiv.y;
        a.w += xr1 * wiv.y + xi1 * wrv.y;
    }
    *(float4*)(ws + OFF_OL + (long)bo * 800 + 4 * t) = a;
}

// ---------------- inverse: OL -> out (fused H-iDFT then symmetric W-iDFT) -------
// grid 4096: (bo, hq); 256 threads; 3 blocks/CU
__launch_bounds__(256, 3)
__global__ void inv_kernel(const float* __restrict__ ws, float* __restrict__ out) {
    __shared__ float sm2[11712];
    float* sOL = sm2;            // 800
    float* cs  = sm2 + 800;      // 512
    float* sYr = sm2 + 1312;     // [20][68]
    float* sYi = sm2 + 2672;     // [20][68]
    float* sTc = sm2 + 4032;     // [20][16][12]
    float* sTs = sm2 + 7872;     // [20][16][12]
    const int t = threadIdx.x;
    const int blk = blockIdx.x;
    const int bo = blk >> 2;     // b*64+o
    const int hq = blk & 3;

    { float ang = TWO_PI * (float)t * (1.0f/256.0f); float s,c; sincosf(ang,&s,&c);
      cs[2*t] = c; cs[2*t+1] = s; }
    {
        const float* OL = ws + OFF_OL + (long)bo * (NMODES * 2);
#pragma unroll
        for (int j = 0; j < 4; ++j) {
            int u = t + 256 * j;
            if (u < 800) sOL[u] = OL[u];
        }
        const float* TI = ws + OFF_TINV;
#pragma unroll
        for (int j = 0; j < 8; ++j) {
            int u = t + 256 * j;
            if (u < 1920) *(float4*)(sTc + 4*u) = *(const float4*)(TI + 4*u);
        }
    }
    __syncthreads();

    // phase 1: Yc[ky][h] = sum_kx OL[kx][ky] e^{+2pi i kx h/256}
    {
        int hloc = t >> 2, kyq = t & 3;
        int h = hq * 64 + hloc;
        float a[5][2];
#pragma unroll
        for (int kk = 0; kk < 5; kk++) { a[kk][0] = 0.f; a[kk][1] = 0.f; }
        for (int kx = 0; kx < NM1; ++kx) {
            int idx = (kx * h) & 255;
            float c = cs[2*idx], s = cs[2*idx+1];
#pragma unroll
            for (int kk = 0; kk < 5; ++kk) {
                int ky = kyq * 5 + kk;
                float pr = sOL[2*(kx*NM2 + ky)], pi = sOL[2*(kx*NM2 + ky) + 1];
                a[kk][0] += pr * c - pi * s;
                a[kk][1] += pr * s + pi * c;
            }
        }
#pragma unroll
        for (int kk = 0; kk < 5; ++kk) {
            int ky = kyq * 5 + kk;
            sYr[ky*68 + hloc] = a[kk][0];
            sYi[ky*68 + hloc] = a[kk][1];
        }
    }
    __syncthreads();

    // phase 2: U = sum_ky Yr*Tc, V = sum_ky Yi*Ts; out[w]=U-V, out[256-w]=U+V
    {
        const int lg = t & 15;
        const int hg = t >> 4;
        float U[4][8], V[4][8];
#pragma unroll
        for (int rr = 0; rr < 4; rr++)
#pragma unroll
            for (int c = 0; c < 8; c++) { U[rr][c] = 0.f; V[rr][c] = 0.f; }
        for (int ky = 0; ky < 20; ++ky) {
            float4 yr = *(const float4*)(sYr + ky*68 + 4*hg);
            float4 yi = *(const float4*)(sYi + ky*68 + 4*hg);
            const float* tcp = sTc + ky*192 + lg*12;
            const float* tsp = sTs + ky*192 + lg*12;
            float4 c0 = *(const float4*)(tcp), c1 = *(const float4*)(tcp + 4);
            float4 s0 = *(const float4*)(tsp), s1 = *(const float4*)(tsp + 4);
            float ya[4] = {yr.x, yr.y, yr.z, yr.w};
            float yb[4] = {yi.x, yi.y, yi.z, yi.w};
            float tc[8] = {c0.x,c0.y,c0.z,c0.w, c1.x,c1.y,c1.z,c1.w};
            float ts[8] = {s0.x,s0.y,s0.z,s0.w, s1.x,s1.y,s1.z,s1.w};
#pragma unroll
            for (int rr = 0; rr < 4; ++rr)
#pragma unroll
                for (int c = 0; c < 8; ++c) {
                    U[rr][c] += ya[rr] * tc[c];
                    V[rr][c] += yb[rr] * ts[c];
                }
        }
        float* orow0 = out + (long)bo * (NH*NW) + (long)(hq*64 + 4*hg) * NW;
#pragma unroll
        for (int rr = 0; rr < 4; ++rr) {
            float* orow = orow0 + (long)rr * NW;
            float L[8], F[8];
#pragma unroll
            for (int c = 0; c < 8; ++c) { L[c] = U[rr][c] - V[rr][c]; F[c] = U[rr][c] + V[rr][c]; }
            int wl = 8*lg + 1;
            orow[wl] = L[0];
            *(float2*)(orow + wl + 1) = make_float2(L[1], L[2]);
            *(float4*)(orow + wl + 3) = make_float4(L[3], L[4], L[5], L[6]);
            orow[wl + 7] = L[7];
            *(float4*)(orow + 252 - 8*lg) = make_float4(F[3], F[2], F[1], F[0]);
            *(float4*)(orow + 248 - 8*lg) = make_float4(F[7], F[6], F[5], F[4]);
        }
    }
    if (t < 64) {
        float sum = 0.f;
        for (int ky = 0; ky < 20; ++ky)
            sum += sYr[ky*68 + t] * ((ky == 0) ? 1.0f : 2.0f);
        out[(long)bo * (NH*NW) + (long)(hq*64 + t) * NW] = sum * INV_N2;
    }
}

extern "C" void kernel_launch(void* const* d_in, const int* in_sizes, int n_in,
                              void* d_out, int out_size, void* d_ws, size_t ws_size,
                              hipStream_t stream) {
    const float* x   = (const float*)d_in[0];
    const float* wre = (const float*)d_in[1];
    const float* wim = (const float*)d_in[2];
    float* out = (float*)d_out;
    float* ws  = (float*)d_ws;

    init_tabs<<<dim3(78), dim3(256), 0, stream>>>(ws);
    fwd_kernel<<<dim3(2 * NB * NCI), dim3(256), 0, stream>>>(x, ws);
    mix_kernel<<<dim3(1024), dim3(256), 0, stream>>>(wre, wim, ws);
    inv_kernel<<<dim3(NB * NCO * 4), dim3(256), 0, stream>>>(ws, out);
}

// Round 19
// 237.406 us; speedup vs baseline: 1.1315x; 1.1182x over previous
//
#include <hip/hip_runtime.h>

constexpr int NB = 16;
constexpr int NCI = 64;
constexpr int NCO = 64;
constexpr int NH = 256;
constexpr int NW = 256;
constexpr int NM1 = 20;
constexpr int NM2 = 20;
constexpr int NMODES = 400;

// workspace layout (float offsets)
constexpr long OFF_TWS  = 0;                                  // fwd twiddle [256 w][48]
constexpr long OFF_TINV = 12288;                              // Tc[20][16][8] | Ts[20][16][8]
constexpr long OFF_XL   = OFF_TINV + 7680;                    // [2 half][NB*NCI][400][2]
constexpr long OFF_OL   = OFF_XL + 2L*NB*NCI*NMODES*2;        // [NB][NCO][400][2]

constexpr float TWO_PI = 6.28318530717958647692f;
constexpr float INV_N2 = 1.0f / 65536.0f;

// async global->LDS, 16 B per lane; LDS dest = wave-uniform base + lane*16
__device__ __forceinline__ void gload16(const float* g, float* l) {
    __builtin_amdgcn_global_load_lds(
        (const __attribute__((address_space(1))) unsigned int*)(g),
        (__attribute__((address_space(3))) unsigned int*)(l), 16, 0, 0);
}

// ---------------- table init ----------------------------------------------------
__global__ void init_tabs(float* __restrict__ ws) {
    int e = blockIdx.x * 256 + threadIdx.x;
    if (e < 12288) {
        int w = e / 48, s = e % 48;
        int cg = s / 12, q = s % 12;
        float v = 0.f;
        if (q < 10) {
            int n = 10 * cg + q, ky = n >> 1, p = n & 1;
            float ang = TWO_PI * (float)((ky * w) & 255) * (1.0f / 256.0f);
            float sn, cn; sincosf(ang, &sn, &cn);
            v = p ? -sn : cn;
        }
        ws[OFF_TWS + e] = v;
    } else if (e < 17408) {
        int f = e - 12288;
        int tb = f / 2560, rr2 = f % 2560;
        int ky = rr2 / 128, g = (rr2 % 128) / 8, q = rr2 % 8;
        int w = 8 * g + 1 + q;
        float ang = TWO_PI * (float)((ky * w) & 255) * (1.0f / 256.0f);
        float sn, cn; sincosf(ang, &sn, &cn);
        float cky = (ky == 0) ? 1.0f : 2.0f;
        ws[OFF_TINV + f] = (tb == 0 ? cn : sn) * cky * INV_N2;
    }
}

// ---------------- forward: x -> X_low partials (radix-2 W-DFT then H-DFT) -------
// grid 2048: block = (plane r, half s); 128 h-rows per block; 256 threads.
// Chunks are 16 w wide with SEPARATE front/back buffers: each gload16 covers
// 16 rows x contiguous 64B (vs 32B interleaved before) -> half the cache-line
// touches per DMA instruction. 34.8 KB LDS -> 4 blocks/CU.
// (256,2): no spill (bound=3 caps VGPR ~84 and spills — 4-for-4 empirical).
__launch_bounds__(256, 2)
__global__ void fwd_kernel(const float* __restrict__ x, float* __restrict__ ws) {
    __shared__ float sm[8704];           // 34816 B: 2 x 4096 dbuf | sA alias | csp
    float* sA = sm;                      // [128][40] phase 2 (aliases buffers)
    float2* csp = (float2*)(sm + 8192);  // [256] cos/sin (persistent, disjoint)
    const int t = threadIdx.x;
    const int bi = blockIdx.x;
    const int r = bi >> 1;                    // plane = b*64+i
    const int s = bi & 1;                     // h-half
    const float* xr = x + ((long)r << 16) + (s << 15);   // rows 128s..128s+127

    const int wid  = t >> 6;                  // n-slice: n = 10*wid + q
    const int lane = t & 63;                  // rows: lane + 64*rr, rr in {0,1}
    const int widu = __builtin_amdgcn_readfirstlane(wid);
    const float* twsu = ws + OFF_TWS + 12 * widu;
    const int keyr = (lane >> 1) & 3;         // read swizzle key (rr-invariant)
    const bool swapEO = (wid & 1);            // ky parity flips with wid (ky=5wid+d)

    // staging: inst ii covers rows 16ii..16ii+15; lane l -> row 16ii+(l>>2),
    // slot l&3 which holds logical quad (l&3)^K(row), K(r)=(r>>1)&3=(l>>3)&3.
    const int jsrc = (lane & 3) ^ ((lane >> 3) & 3);
    const int lrow = lane >> 2;

    float acc[2][10];
#pragma unroll
    for (int a0 = 0; a0 < 2; a0++)
#pragma unroll
        for (int a1 = 0; a1 < 10; a1++) acc[a0][a1] = 0.f;

#define STAGE(KC, BUF)                                                         \
    {                                                                          \
        const float* xf_ = xr + (KC) * 16 + 4 * jsrc;                          \
        _Pragma("unroll")                                                      \
        for (int ii = 0; ii < 8; ++ii) {                                       \
            const long rb_ = (long)(ii * 16 + lrow) * NW;                      \
            gload16(xf_ + rb_,       (BUF) + ii * 256);          /* front */   \
            gload16(xf_ + rb_ + 128, (BUF) + 2048 + ii * 256);   /* back  */   \
        }                                                                      \
    }

    {
        float ang = TWO_PI * (float)t * (1.0f / 256.0f);
        float sn, cn; sincosf(ang, &sn, &cn);
        csp[t] = make_float2(cn, sn);
    }
    STAGE(0, sm);
    __syncthreads();   // chunk 0 staged & visible

    for (int kc = 0; kc < 8; ++kc) {
        float* buf = sm + (kc & 1) * 4096;
        if (kc < 7) STAGE(kc + 1, sm + ((kc + 1) & 1) * 4096);
#pragma unroll
        for (int g = 0; g < 4; ++g) {
            float4 f4[2], b4[2];
#pragma unroll
            for (int rr = 0; rr < 2; ++rr) {
                const int off = (lane + 64 * rr) * 16 + 4 * (g ^ keyr);
                f4[rr] = *(const float4*)(buf + off);
                b4[rr] = *(const float4*)(buf + 2048 + off);
            }
#pragma unroll
            for (int e = 0; e < 4; ++e) {
                const float* tp = twsu + (long)(kc * 16 + 4 * g + e) * 48;
                float4 t0 = *(const float4*)(tp);
                float4 t1 = *(const float4*)(tp + 4);
                float4 t2 = *(const float4*)(tp + 8);
                float tv[10] = {t0.x,t0.y,t0.z,t0.w, t1.x,t1.y,t1.z,t1.w, t2.x,t2.y};
#pragma unroll
                for (int rr = 0; rr < 2; ++rr) {
                    float fv = f4[rr][e], bv = b4[rr][e];
                    float mu = fv + bv, mv = fv - bv;
                    float mE = swapEO ? mv : mu;
                    float mO = swapEO ? mu : mv;
                    acc[rr][0] += mE * tv[0];  acc[rr][1] += mE * tv[1];
                    acc[rr][2] += mO * tv[2];  acc[rr][3] += mO * tv[3];
                    acc[rr][4] += mE * tv[4];  acc[rr][5] += mE * tv[5];
                    acc[rr][6] += mO * tv[6];  acc[rr][7] += mO * tv[7];
                    acc[rr][8] += mE * tv[8];  acc[rr][9] += mE * tv[9];
                }
            }
        }
        __syncthreads();   // compute(kc) done everywhere; prefetch(kc+1) drained
    }
#undef STAGE

    // write A[hl][n] to LDS (csp persists)
#pragma unroll
    for (int rr = 0; rr < 2; ++rr)
#pragma unroll
        for (int q = 0; q < 10; ++q)
            sA[(lane + 64 * rr) * 40 + 10 * wid + q] = acc[rr][q];
    __syncthreads();

    // phase 2 (partial): XLp[s][kx,ky] = sum_{hl<128} A[hl][.] e^{-2pi i kx h/256},
    // h = 128*s + hl
    if (t < 200) {
        const int p  = t >> 1;         // 0..99
        const int sh = t & 1;          // 64-row sub-half; partner = adjacent lane
        const int kxg = p / 10, kyg = p % 10;
        const int kx0 = 2 * kxg;
        float a2[8];
#pragma unroll
        for (int q = 0; q < 8; q++) a2[q] = 0.f;
        for (int it = 0; it < 64; ++it) {
            int hl = 64 * sh + it;
            int hg = 128 * s + hl;
            float4 a = *(const float4*)(sA + hl * 40 + 4 * kyg); // re0,im0,re1,im1
            int i0 = (kx0 * hg) & 255;
            int i1 = (i0 + hg) & 255;
            float2 cs0 = csp[i0];
            float2 cs1 = csp[i1];
            a2[0] += a.x*cs0.x + a.y*cs0.y;  a2[1] += a.y*cs0.x - a.x*cs0.y;
            a2[2] += a.z*cs0.x + a.w*cs0.y;  a2[3] += a.w*cs0.x - a.z*cs0.y;
            a2[4] += a.x*cs1.x + a.y*cs1.y;  a2[5] += a.y*cs1.x - a.x*cs1.y;
            a2[6] += a.z*cs1.x + a.w*cs1.y;  a2[7] += a.w*cs1.x - a.z*cs1.y;
        }
#pragma unroll
        for (int q = 0; q < 8; q++) a2[q] += __shfl_xor(a2[q], 1);
        if (sh == 0) {
            float* xl = ws + OFF_XL + ((long)s * (NB * NCI) + r) * (NMODES * 2);
            *(float4*)(xl + 2*(kx0*20 + 2*kyg))       = make_float4(a2[0],a2[1],a2[2],a2[3]);
            *(float4*)(xl + 2*((kx0+1)*20 + 2*kyg))   = make_float4(a2[4],a2[5],a2[6],a2[7]);
        }
    }
}

// ---------------- channel mix: OL[b,o,m] = sum_i (XLp0+XLp1)[b,i,m]*W[i,o,m] ----
// grid 1024: bo = b*64+o; no LDS, no barriers; direct L2-resident reads.
__launch_bounds__(256, 4)
__global__ void mix_kernel(const float* __restrict__ wre, const float* __restrict__ wim,
                           float* __restrict__ ws) {
    const int t = threadIdx.x;
    const int bo = blockIdx.x;
    const int b = bo >> 6, o = bo & 63;
    if (t >= 200) return;
    const float* XL0 = ws + OFF_XL + (long)(b * 64) * 800 + 4 * t;
    const float* XL1 = XL0 + (long)(NB * NCI) * 800;
    const float* wrp = wre + (long)o * NMODES + 2 * t;
    const float* wip = wim + (long)o * NMODES + 2 * t;
    float4 a = make_float4(0.f, 0.f, 0.f, 0.f);
#pragma unroll 4
    for (int i = 0; i < 64; ++i) {
        float4 x0 = *(const float4*)(XL0 + (long)i * 800);
        float4 x1 = *(const float4*)(XL1 + (long)i * 800);
        float2 wrv = *(const float2*)(wrp + (long)i * (NCO * NMODES));
        float2 wiv = *(const float2*)(wip + (long)i * (NCO * NMODES));
        float xr0 = x0.x + x1.x, xi0 = x0.y + x1.y;
        float xr1 = x0.z + x1.z, xi1 = x0.w + x1.w;
        a.x += xr0 * wrv.x - xi0 * wiv.x;
        a.y += xr0 * wiv.x + xi0 * wrv.x;
        a.z += xr1 * wrv.y - xi1 * wiv.y;
        a.w += xr1 * wiv.y + xi1 * wrv.y;
    }
    *(float4*)(ws + OFF_OL + (long)bo * 800 + 4 * t) = a;
}

// ---------------- inverse: OL -> out (fused H-iDFT then symmetric W-iDFT) -------
// grid 4096: (bo, hq); 256 threads. Packed T [20][16][8] (pad dropped):
// LDS 36.6 KB -> 4 blocks/CU (was 46.8 KB / 3).
__launch_bounds__(256, 3)
__global__ void inv_kernel(const float* __restrict__ ws, float* __restrict__ out) {
    __shared__ float sm2[9152];
    float* sOL = sm2;            // 800
    float* cs  = sm2 + 800;      // 512
    float* sYr = sm2 + 1312;     // [20][68]
    float* sYi = sm2 + 2672;     // [20][68]
    float* sTc = sm2 + 4032;     // [20][16][8]
    float* sTs = sm2 + 6592;     // [20][16][8]
    const int t = threadIdx.x;
    const int blk = blockIdx.x;
    const int bo = blk >> 2;     // b*64+o
    const int hq = blk & 3;

    { float ang = TWO_PI * (float)t * (1.0f/256.0f); float s,c; sincosf(ang,&s,&c);
      cs[2*t] = c; cs[2*t+1] = s; }
    {
        const float* OL = ws + OFF_OL + (long)bo * (NMODES * 2);
#pragma unroll
        for (int j = 0; j < 4; ++j) {
            int u = t + 256 * j;
            if (u < 800) sOL[u] = OL[u];
        }
        const float* TI = ws + OFF_TINV;
#pragma unroll
        for (int j = 0; j < 5; ++j) {
            int u = t + 256 * j;
            if (u < 1280) *(float4*)(sTc + 4*u) = *(const float4*)(TI + 4*u);
        }
    }
    __syncthreads();

    // phase 1: Yc[ky][h] = sum_kx OL[kx][ky] e^{+2pi i kx h/256}
    {
        int hloc = t >> 2, kyq = t & 3;
        int h = hq * 64 + hloc;
        float a[5][2];
#pragma unroll
        for (int kk = 0; kk < 5; kk++) { a[kk][0] = 0.f; a[kk][1] = 0.f; }
        for (int kx = 0; kx < NM1; ++kx) {
            int idx = (kx * h) & 255;
            float c = cs[2*idx], s = cs[2*idx+1];
#pragma unroll
            for (int kk = 0; kk < 5; ++kk) {
                int ky = kyq * 5 + kk;
                float pr = sOL[2*(kx*NM2 + ky)], pi = sOL[2*(kx*NM2 + ky) + 1];
                a[kk][0] += pr * c - pi * s;
                a[kk][1] += pr * s + pi * c;
            }
        }
#pragma unroll
        for (int kk = 0; kk < 5; ++kk) {
            int ky = kyq * 5 + kk;
            sYr[ky*68 + hloc] = a[kk][0];
            sYi[ky*68 + hloc] = a[kk][1];
        }
    }
    __syncthreads();

    // phase 2: U = sum_ky Yr*Tc, V = sum_ky Yi*Ts; out[w]=U-V, out[256-w]=U+V
    {
        const int lg = t & 15;
        const int hg = t >> 4;
        float U[4][8], V[4][8];
#pragma unroll
        for (int rr = 0; rr < 4; rr++)
#pragma unroll
            for (int c = 0; c < 8; c++) { U[rr][c] = 0.f; V[rr][c] = 0.f; }
        for (int ky = 0; ky < 20; ++ky) {
            float4 yr = *(const float4*)(sYr + ky*68 + 4*hg);
            float4 yi = *(const float4*)(sYi + ky*68 + 4*hg);
            const float* tcp = sTc + ky*128 + lg*8;
            const float* tsp = sTs + ky*128 + lg*8;
            float4 c0 = *(const float4*)(tcp), c1 = *(const float4*)(tcp + 4);
            float4 s0 = *(const float4*)(tsp), s1 = *(const float4*)(tsp + 4);
            float ya[4] = {yr.x, yr.y, yr.z, yr.w};
            float yb[4] = {yi.x, yi.y, yi.z, yi.w};
            float tc[8] = {c0.x,c0.y,c0.z,c0.w, c1.x,c1.y,c1.z,c1.w};
            float ts[8] = {s0.x,s0.y,s0.z,s0.w, s1.x,s1.y,s1.z,s1.w};
#pragma unroll
            for (int rr = 0; rr < 4; ++rr)
#pragma unroll
                for (int c = 0; c < 8; ++c) {
                    U[rr][c] += ya[rr] * tc[c];
                    V[rr][c] += yb[rr] * ts[c];
                }
        }
        float* orow0 = out + (long)bo * (NH*NW) + (long)(hq*64 + 4*hg) * NW;
#pragma unroll
        for (int rr = 0; rr < 4; ++rr) {
            float* orow = orow0 + (long)rr * NW;
            float L[8], F[8];
#pragma unroll
            for (int c = 0; c < 8; ++c) { L[c] = U[rr][c] - V[rr][c]; F[c] = U[rr][c] + V[rr][c]; }
            int wl = 8*lg + 1;
            orow[wl] = L[0];
            *(float2*)(orow + wl + 1) = make_float2(L[1], L[2]);
            *(float4*)(orow + wl + 3) = make_float4(L[3], L[4], L[5], L[6]);
            orow[wl + 7] = L[7];
            *(float4*)(orow + 252 - 8*lg) = make_float4(F[3], F[2], F[1], F[0]);
            *(float4*)(orow + 248 - 8*lg) = make_float4(F[7], F[6], F[5], F[4]);
        }
    }
    if (t < 64) {
        float sum = 0.f;
        for (int ky = 0; ky < 20; ++ky)
            sum += sYr[ky*68 + t] * ((ky == 0) ? 1.0f : 2.0f);
        out[(long)bo * (NH*NW) + (long)(hq*64 + t) * NW] = sum * INV_N2;
    }
}

extern "C" void kernel_launch(void* const* d_in, const int* in_sizes, int n_in,
                              void* d_out, int out_size, void* d_ws, size_t ws_size,
                              hipStream_t stream) {
    const float* x   = (const float*)d_in[0];
    const float* wre = (const float*)d_in[1];
    const float* wim = (const float*)d_in[2];
    float* out = (float*)d_out;
    float* ws  = (float*)d_ws;

    init_tabs<<<dim3(68), dim3(256), 0, stream>>>(ws);
    fwd_kernel<<<dim3(2 * NB * NCI), dim3(256), 0, stream>>>(x, ws);
    mix_kernel<<<dim3(1024), dim3(256), 0, stream>>>(wre, wim, ws);
    inv_kernel<<<dim3(NB * NCO * 4), dim3(256), 0, stream>>>(ws, out);
}